// Round 12
// baseline (1147.046 us; speedup 1.0000x reference)
//
#include <hip/hip_runtime.h>
#include <math.h>

// Sinkhorn loss, B=8, S=2048, P=1024, D=2, eps=0.01, 50 iters.
// PERSISTENT-KERNEL v12 — dual-batch interleave with R9-SHAPED phases.
// History: R9 (567us) = barrier + staging, stall ~270us (100 x 2.7us L3
// settle+poll+staging, zero overlap). R10 dual-batch REGRESSED from phase
// bloat (quarter-tile g-split: +75us VALU in butterflies/merges, 4 syncs of
// half-size cover). R11 stamped dataflow REGRESSED (poll re-fetch traffic:
// FETCH 21->87MB). v12 keeps R10's schedule idea but with R9's exact loop
// shapes: f = 2 rows/wave full-tile, g = 1 col/wave full-tile (NO LDS
// merge, butterfly count identical to R9), 64 blocks/batch, rotation
// fA->fB->gA->gB where each wait has one full phase (~1.5us) of cover:
//   wait(gdA,it)<-prev gB | wait(gdB,it)<-fA | wait(fdA)<-fB | wait(fdB)<-gA
// WAR-safe single-buffered (R10 argument): gA(it) overwrites G2A only after
// wait(fdA,it+1) => every block finished its fA staging reads of G2A.
// g-phase x-coords from L1-hot global float4 (R10-proven) to fit LDS ~41KB.
// Base-2 scaled potentials: F2 = f/(eps*ln2), G2 = g/(eps*ln2), K = 100*log2(e)
//   f elem: u = 2K*x.y + (G2[p] - K*y2[p]);  F2 = (K*x2 - log2 S) - LSE2(u)
//   g elem: u = 2K*x.y + (F2[s] - K*x2[s]);  G2 = (K*y2 + logb2) - LSE2(u)

#define BB 8
#define SS 2048
#define PP 1024
#define NEG_INF -1e9f
#define LOG2S 11.0f
#define ITERS 50
#define K2E 144.269504088896f   /* 100*log2(e) */
#define TWOK 288.539008177792f  /* 200*log2(e) */
#define NBLK 256
#define NTHR 1024

typedef float v2f __attribute__((ext_vector_type(2)));

__device__ __forceinline__ float fexp2(float x) {
  return __builtin_amdgcn_exp2f(x);
}
__device__ __forceinline__ float flog2(float x) {
  return __builtin_amdgcn_logf(x);
}
__device__ __forceinline__ v2f vfma(v2f a, v2f b, v2f c) {
  return __builtin_elementwise_fma(a, b, c);
}
__device__ __forceinline__ v2f vmax(v2f a, v2f b) {
  return __builtin_elementwise_max(a, b);
}

// agent-scope coherent (cache-bypassing) accessors, RELAXED only (proven R6+)
__device__ __forceinline__ float coh_load(const float* p) {
  return __hip_atomic_load((float*)p, __ATOMIC_RELAXED, __HIP_MEMORY_SCOPE_AGENT);
}
__device__ __forceinline__ void coh_store(float* p, float v) {
  __hip_atomic_store(p, v, __ATOMIC_RELAXED, __HIP_MEMORY_SCOPE_AGENT);
}
__device__ __forceinline__ int coh_loadi(const int* p) {
  return __hip_atomic_load((int*)p, __ATOMIC_RELAXED, __HIP_MEMORY_SCOPE_AGENT);
}
__device__ __forceinline__ void coh_storei(int* p, int v) {
  __hip_atomic_store(p, v, __ATOMIC_RELAXED, __HIP_MEMORY_SCOPE_AGENT);
}

// split barrier (proven R10): arrive = syncthreads (drains all waves' stores)
// + t0 posts version; wait = wave0 polls 64 slots one-per-lane until __all.
__device__ __forceinline__ void arrive(int* slot, int ver) {
  __syncthreads();
  asm volatile("" ::: "memory");
  if (threadIdx.x == 0) coh_storei(slot, ver);
}
__device__ __forceinline__ void wait_all(int* slots, int ver, int w, int lane) {
  if (w == 0) {
    for (;;) {
      int v = coh_loadi(&slots[lane]);
      if (__all(v >= ver)) break;
      __builtin_amdgcn_s_sleep(1);
    }
  }
  asm volatile("" ::: "memory");
  __syncthreads();
}

// ws layout (bytes):
//   G2    : [0,      32768)   B*P float
//   F2    : [32768,  98304)   B*S float
//   logb2 : [98304, 131072)   B*P float
//   fdone : [131072, 133120)  8 batches x 64 ints (version slots)
//   gdone : [133120, 135168)  8 batches x 64 ints

__global__ __launch_bounds__(1024) void setup_kernel(
    const int* __restrict__ labels, float* __restrict__ G2,
    float* __restrict__ logb2, int* __restrict__ fdone,
    int* __restrict__ gdone, float* __restrict__ out) {
  __shared__ int c[PP];
  int b = blockIdx.x;
  int t = threadIdx.x;  // 1024 threads
  c[t] = 0;
  __syncthreads();
  atomicAdd(&c[labels[b * SS + t] & (PP - 1)], 1);
  atomicAdd(&c[labels[b * SS + PP + t] & (PP - 1)], 1);
  __syncthreads();
  int cc = c[t];
  logb2[b * PP + t] = (cc > 0) ? (flog2((float)cc) - LOG2S) : NEG_INF;
  G2[b * PP + t] = 0.0f;
  if (t < 64) {
    fdone[(b << 6) + t] = 0;
    gdone[(b << 6) + t] = 0;
  }
  if (t == 0 && b == 0) out[0] = 0.0f;
}

// f-phase: 2 rows/wave, full 1024-col tile from LDS SoA, pk online LSE
// (R9 loop with r<2). Lanes 0..1 store the 2 rows to F2out.
__device__ __forceinline__ void f_phase2(const float* fy0, const float* fy1,
                                         const float* fq,
                                         const float2* preds2, int frow,
                                         float* F2out, int lane) {
  float2 fx0 = preds2[frow];
  float2 fx1 = preds2[frow + 1];
  float fk0[2] = {TWOK * fx0.x, TWOK * fx1.x};
  float fk1[2] = {TWOK * fx0.y, TWOK * fx1.y};
  float fc0[2] = {fmaf(K2E, fx0.x * fx0.x + fx0.y * fx0.y, -LOG2S),
                  fmaf(K2E, fx1.x * fx1.x + fx1.y * fx1.y, -LOG2S)};
  float m[2];
  v2f s[2];
#pragma unroll
  for (int r = 0; r < 2; ++r) { m[r] = -3.4e38f; s[r] = (v2f)(0.0f); }
#pragma unroll
  for (int ch = 0; ch < 2; ++ch) {
    v2f a0[4], a1[4], aq[4];
#pragma unroll
    for (int i = 0; i < 4; ++i) {
      int pi = (ch << 8) + (i << 6) + lane;  // pair index, consecutive lanes
      a0[i] = *(const v2f*)&fy0[pi << 1];
      a1[i] = *(const v2f*)&fy1[pi << 1];
      aq[i] = *(const v2f*)&fq[pi << 1];
    }
#pragma unroll
    for (int r = 0; r < 2; ++r) {
      v2f K0 = (v2f)(fk0[r]), K1 = (v2f)(fk1[r]);
      v2f u0 = vfma(K0, a0[0], vfma(K1, a1[0], aq[0]));
      v2f u1 = vfma(K0, a0[1], vfma(K1, a1[1], aq[1]));
      v2f u2 = vfma(K0, a0[2], vfma(K1, a1[2], aq[2]));
      v2f u3 = vfma(K0, a0[3], vfma(K1, a1[3], aq[3]));
      v2f cm2 = vmax(vmax(u0, u1), vmax(u2, u3));
      float mn = fmaxf(m[r], fmaxf(cm2.x, cm2.y));
      float sc = fexp2(m[r] - mn);
      v2f mn2 = (v2f)(mn);
      v2f d0 = u0 - mn2, d1 = u1 - mn2, d2 = u2 - mn2, d3 = u3 - mn2;
      v2f e0 = {fexp2(d0.x), fexp2(d0.y)};
      v2f e1 = {fexp2(d1.x), fexp2(d1.y)};
      v2f e2 = {fexp2(d2.x), fexp2(d2.y)};
      v2f e3 = {fexp2(d3.x), fexp2(d3.y)};
      s[r] = vfma(s[r], (v2f)(sc), (e0 + e1) + (e2 + e3));
      m[r] = mn;
    }
  }
  float fout = 0.0f;
#pragma unroll
  for (int r = 0; r < 2; ++r) {
    float M = m[r];
#pragma unroll
    for (int off = 1; off <= 32; off <<= 1)
      M = fmaxf(M, __shfl_xor(M, off, 64));
    float sr = (s[r].x + s[r].y) * fexp2(m[r] - M);
#pragma unroll
    for (int off = 1; off <= 32; off <<= 1) sr += __shfl_xor(sr, off, 64);
    float v = fc0[r] - M - flog2(sr);
    if (lane == r) fout = v;
  }
  if (lane < 2) coh_store(&F2out[lane], fout);
}

// g-phase: 1 col/wave, full 2048-row tile; x from L1-hot global float4,
// q from LDS; pk online LSE (R9 loop with single col). Lane 0 stores.
__device__ __forceinline__ void g_phase1(const float4* x4, const float* gq,
                                         const float2* pos2,
                                         const float* __restrict__ logb2,
                                         int gcol, float* G2out, int lane) {
  float2 gy = pos2[gcol];
  float gk0 = TWOK * gy.x, gk1 = TWOK * gy.y;
  float gc0 = fmaf(K2E, gy.x * gy.x + gy.y * gy.y, logb2[gcol]);
  float m = -3.4e38f;
  v2f s = (v2f)(0.0f);
#pragma unroll
  for (int ch = 0; ch < 4; ++ch) {
    v2f a0[4], a1[4], aq[4];
#pragma unroll
    for (int i = 0; i < 4; ++i) {
      int pi = (ch << 8) + (i << 6) + lane;
      float4 v = x4[pi];               // (x0,x1,x0',x1') — L1-hot
      a0[i] = (v2f){v.x, v.z};
      a1[i] = (v2f){v.y, v.w};
      aq[i] = *(const v2f*)&gq[pi << 1];
    }
    v2f K0 = (v2f)(gk0), K1 = (v2f)(gk1);
    v2f u0 = vfma(K0, a0[0], vfma(K1, a1[0], aq[0]));
    v2f u1 = vfma(K0, a0[1], vfma(K1, a1[1], aq[1]));
    v2f u2 = vfma(K0, a0[2], vfma(K1, a1[2], aq[2]));
    v2f u3 = vfma(K0, a0[3], vfma(K1, a1[3], aq[3]));
    v2f cm2 = vmax(vmax(u0, u1), vmax(u2, u3));
    float mn = fmaxf(m, fmaxf(cm2.x, cm2.y));
    float sc = fexp2(m - mn);
    v2f mn2 = (v2f)(mn);
    v2f d0 = u0 - mn2, d1 = u1 - mn2, d2 = u2 - mn2, d3 = u3 - mn2;
    v2f e0 = {fexp2(d0.x), fexp2(d0.y)};
    v2f e1 = {fexp2(d1.x), fexp2(d1.y)};
    v2f e2 = {fexp2(d2.x), fexp2(d2.y)};
    v2f e3 = {fexp2(d3.x), fexp2(d3.y)};
    s = vfma(s, (v2f)(sc), (e0 + e1) + (e2 + e3));
    m = mn;
  }
  float M = m;
#pragma unroll
  for (int off = 1; off <= 32; off <<= 1)
    M = fmaxf(M, __shfl_xor(M, off, 64));
  float sr = (s.x + s.y) * fexp2(m - M);
#pragma unroll
  for (int off = 1; off <= 32; off <<= 1) sr += __shfl_xor(sr, off, 64);
  if (lane == 0) coh_store(G2out, gc0 - M - flog2(sr));
}

__global__ __launch_bounds__(1024) void sinkhorn_persist(
    const float* __restrict__ preds, const float* __restrict__ pos,
    const float* __restrict__ logb2, float* __restrict__ F2g,
    float* __restrict__ G2g, int* __restrict__ fdone,
    int* __restrict__ gdone, float* __restrict__ out) {
  __shared__ __align__(16) float fy0A[PP], fy1A[PP], fqA[PP];  // 12 KB
  __shared__ __align__(16) float fy0B[PP], fy1B[PP], fqB[PP];  // 12 KB
  __shared__ __align__(16) float gqA[SS], gqB[SS];             // 16 KB
  __shared__ float spart;
  const int t = threadIdx.x;    // 1024 threads, 16 waves
  const int blk = blockIdx.x;   // 256 blocks = 1/CU (proven geometry)
  const int grp = blk >> 6;     // 4 groups x 64 blocks
  const int sub = blk & 63;
  const int bbA = grp << 1, bbB = (grp << 1) + 1;
  int* fdA = fdone + (bbA << 6);
  int* fdB = fdone + (bbB << 6);
  int* gdA = gdone + (bbA << 6);
  int* gdB = gdone + (bbB << 6);
  const float2* pos2 = (const float2*)pos;
  const float2* preds2 = (const float2*)preds;
  const float4* xA4 = (const float4*)(preds + ((size_t)bbA << 12));
  const float4* xB4 = (const float4*)(preds + ((size_t)bbB << 12));
  float* G2A = G2g + (bbA << 10);
  float* G2B = G2g + (bbB << 10);
  float* F2A = F2g + (bbA << 11);
  float* F2B = F2g + (bbB << 11);

  // ---- persistent init: y coords into LDS SoA + K-scale norms in regs
  float yr2A, yr2B, xr2A[2], xr2B[2];
  {
    float2 y = pos2[(bbA << 10) + t];
    yr2A = y.x * y.x + y.y * y.y;
    fy0A[t] = y.x;
    fy1A[t] = y.y;
  }
  {
    float2 y = pos2[(bbB << 10) + t];
    yr2B = y.x * y.x + y.y * y.y;
    fy0B[t] = y.x;
    fy1B[t] = y.y;
  }
#pragma unroll
  for (int k = 0; k < 2; ++k) {
    int e = t + (k << 10);
    float2 xa = preds2[(bbA << 11) + e];
    xr2A[k] = xa.x * xa.x + xa.y * xa.y;
    float2 xb = preds2[(bbB << 11) + e];
    xr2B[k] = xb.x * xb.x + xb.y * xb.y;
  }

  const int w = t >> 6, lane = t & 63;
  const int frowA = (bbA << 11) + (sub << 5) + (w << 1);  // 2 f-rows/wave
  const int frowB = (bbB << 11) + (sub << 5) + (w << 1);
  const int gcolA = (bbA << 10) + (sub << 4) + w;          // 1 g-col/wave
  const int gcolB = (bbB << 10) + (sub << 4) + w;

  for (int it = 0; it < ITERS; ++it) {
    // ===== fA: needs gA(it-1); settle covered by previous gB =====
    wait_all(gdA, it, w, lane);
    fqA[t] = fmaf(-K2E, yr2A, coh_load(&G2A[t]));
    __syncthreads();
    f_phase2(fy0A, fy1A, fqA, preds2, frowA, F2g + frowA, lane);
    arrive(&fdA[sub], it + 1);

    // ===== fB: settle covered by fA =====
    wait_all(gdB, it, w, lane);
    fqB[t] = fmaf(-K2E, yr2B, coh_load(&G2B[t]));
    __syncthreads();
    f_phase2(fy0B, fy1B, fqB, preds2, frowB, F2g + frowB, lane);
    arrive(&fdB[sub], it + 1);

    // ===== gA: needs fA(it); settle covered by fB =====
    wait_all(fdA, it + 1, w, lane);
#pragma unroll
    for (int k = 0; k < 2; ++k) {
      int e = t + (k << 10);
      gqA[e] = fmaf(-K2E, xr2A[k], coh_load(&F2A[e]));
    }
    __syncthreads();
    g_phase1(xA4, gqA, pos2, logb2, gcolA, G2g + gcolA, lane);
    arrive(&gdA[sub], it + 1);

    // ===== gB: settle covered by gA =====
    wait_all(fdB, it + 1, w, lane);
#pragma unroll
    for (int k = 0; k < 2; ++k) {
      int e = t + (k << 10);
      gqB[e] = fmaf(-K2E, xr2B[k], coh_load(&F2B[e]));
    }
    __syncthreads();
    g_phase1(xB4, gqB, pos2, logb2, gcolB, G2g + gcolB, lane);
    arrive(&gdB[sub], it + 1);
  }

  // ---- fused final: restage with final potentials, rowsum 32+32 rows
  wait_all(gdA, ITERS, w, lane);
  wait_all(gdB, ITERS, w, lane);
  if (t == 0) spart = 0.0f;
  fqA[t] = fmaf(-K2E, yr2A, coh_load(&G2A[t]));
  fqB[t] = fmaf(-K2E, yr2B, coh_load(&G2B[t]));
  __syncthreads();
  float acc = 0.0f;
#pragma unroll
  for (int rr = 0; rr < 2; ++rr) {
    int row = frowA + rr;
    float2 x = preds2[row];
    float x2 = x.x * x.x + x.y * x.y;
    float qx = fmaf(-K2E, x2, coh_load(&F2g[row]));
#pragma unroll
    for (int i = 0; i < 16; ++i) {
      int p = (i << 6) + lane;
      float ay0 = fy0A[p], ay1 = fy1A[p], aqz = fqA[p];
      float y2 = fmaf(ay0, ay0, ay1 * ay1);
      float tt = fmaf(x.y, ay1, x.x * ay0);
      float c = fmaxf(x2 + y2 - 2.0f * tt, 0.0f);  // clamped cost
      float v2 = fmaf(TWOK, tt, aqz + qx);         // -K*C' + F2 + G2 (base-2)
      acc = fmaf(fexp2(v2), c, acc);               // c==0 kills C'<0 case
    }
  }
#pragma unroll
  for (int rr = 0; rr < 2; ++rr) {
    int row = frowB + rr;
    float2 x = preds2[row];
    float x2 = x.x * x.x + x.y * x.y;
    float qx = fmaf(-K2E, x2, coh_load(&F2g[row]));
#pragma unroll
    for (int i = 0; i < 16; ++i) {
      int p = (i << 6) + lane;
      float ay0 = fy0B[p], ay1 = fy1B[p], aqz = fqB[p];
      float y2 = fmaf(ay0, ay0, ay1 * ay1);
      float tt = fmaf(x.y, ay1, x.x * ay0);
      float c = fmaxf(x2 + y2 - 2.0f * tt, 0.0f);
      float v2 = fmaf(TWOK, tt, aqz + qx);
      acc = fmaf(fexp2(v2), c, acc);
    }
  }
#pragma unroll
  for (int off = 32; off; off >>= 1) acc += __shfl_xor(acc, off, 64);
  if (lane == 0) atomicAdd(&spart, acc);
  __syncthreads();
  if (t == 0) atomicAdd(out, spart * (1.0f / (float)BB));
}

extern "C" void kernel_launch(void* const* d_in, const int* in_sizes, int n_in,
                              void* d_out, int out_size, void* d_ws,
                              size_t ws_size, hipStream_t stream) {
  const float* preds = (const float*)d_in[0];  // [B,S,2]
  const int* labels = (const int*)d_in[1];     // [B,S]
  const float* pos = (const float*)d_in[2];    // [B,P,2]
  float* out = (float*)d_out;
  char* ws = (char*)d_ws;
  float* G2 = (float*)(ws);
  float* F2 = (float*)(ws + 32768);
  float* logb2 = (float*)(ws + 98304);
  int* fdone = (int*)(ws + 131072);
  int* gdone = (int*)(ws + 133120);

  hipLaunchKernelGGL(setup_kernel, dim3(BB), dim3(1024), 0, stream, labels, G2,
                     logb2, fdone, gdone, out);
  hipLaunchKernelGGL(sinkhorn_persist, dim3(NBLK), dim3(NTHR), 0, stream,
                     preds, pos, logb2, F2, G2, fdone, gdone, out);
}

// Round 13
// 550.455 us; speedup vs baseline: 2.0838x; 2.0838x over previous
//
#include <hip/hip_runtime.h>
#include <math.h>

// Sinkhorn loss, B=8, S=2048, P=1024, D=2, eps=0.01, 50 iters.
// PERSISTENT-KERNEL v13 — R9 (567us, best) + XCD-LOCAL batch mapping.
// R10/R11/R12 post-mortems: all overlap restructures regressed by adding
// memory traffic (R12: FETCH 21MB->1.1GB). R9's residual = ~295us compute
// + ~270us of 100 serialized sync settles. Untested lever: R9's batch =
// blk>>5 spreads each batch's 32 blocks over all 8 XCDs (blk%8 = XCD), so
// every exchange crosses the fabric. v13: batch = blk&7 -> all 32 blocks
// of a batch on ONE XCD (32 CUs/XCD, 1 blk/CU exact fit); exchange and
// slot polls become XCD-local, 8 batches' sync traffic disjoint.
// Correctness is mapping-independent. Everything else = R9 verbatim.
// Base-2 scaled potentials: F2 = f/(eps*ln2), G2 = g/(eps*ln2), K = 100*log2(e)
//   f elem: u = 2K*x.y + (G2[p] - K*y2[p]);  F2 = (K*x2 - log2 S) - LSE2(u)
//   g elem: u = 2K*x.y + (F2[s] - K*x2[s]);  G2 = (K*y2 + logb2) - LSE2(u)

#define BB 8
#define SS 2048
#define PP 1024
#define NEG_INF -1e9f
#define LOG2S 11.0f
#define ITERS 50
#define K2E 144.269504088896f   /* 100*log2(e) */
#define TWOK 288.539008177792f  /* 200*log2(e) */
#define NBLK 256
#define NTHR 1024

typedef float v2f __attribute__((ext_vector_type(2)));

__device__ __forceinline__ float fexp2(float x) {
  return __builtin_amdgcn_exp2f(x);
}
__device__ __forceinline__ float flog2(float x) {
  return __builtin_amdgcn_logf(x);
}
__device__ __forceinline__ v2f vfma(v2f a, v2f b, v2f c) {
  return __builtin_elementwise_fma(a, b, c);
}
__device__ __forceinline__ v2f vmax(v2f a, v2f b) {
  return __builtin_elementwise_max(a, b);
}

// agent-scope coherent (cache-bypassing) accessors, RELAXED only (proven R6+)
__device__ __forceinline__ float coh_load(const float* p) {
  return __hip_atomic_load((float*)p, __ATOMIC_RELAXED, __HIP_MEMORY_SCOPE_AGENT);
}
__device__ __forceinline__ void coh_store(float* p, float v) {
  __hip_atomic_store(p, v, __ATOMIC_RELAXED, __HIP_MEMORY_SCOPE_AGENT);
}
__device__ __forceinline__ int coh_loadi(const int* p) {
  return __hip_atomic_load((int*)p, __ATOMIC_RELAXED, __HIP_MEMORY_SCOPE_AGENT);
}
__device__ __forceinline__ void coh_storei(int* p, int v) {
  __hip_atomic_store(p, v, __ATOMIC_RELAXED, __HIP_MEMORY_SCOPE_AGENT);
}

// 32-block per-batch barrier, RMW-free (proven R7/R9): block stores its phase
// to its own slot; wave 0 polls the 32 slots (one per lane) until __all.
__device__ __forceinline__ void batch_barrier(int* slots, int sub, int phase,
                                              int w, int lane) {
  __syncthreads();
  asm volatile("" ::: "memory");
  if (threadIdx.x == 0) coh_storei(&slots[sub], phase);
  if (w == 0) {
    for (;;) {
      int v = (lane < 32) ? coh_loadi(&slots[lane]) : 0x7fffffff;
      if (__all(v >= phase)) break;
      __builtin_amdgcn_s_sleep(1);
    }
  }
  asm volatile("" ::: "memory");
  __syncthreads();
}

// ws layout (bytes):
//   G2    : [0,      32768)   B*P float
//   F2    : [32768,  98304)   B*S float
//   logb2 : [98304, 131072)   B*P float
//   slots : [131072, 132096)  8 batches x 32 ints (phase slots)

__global__ __launch_bounds__(1024) void setup_kernel(
    const int* __restrict__ labels, float* __restrict__ G2,
    float* __restrict__ logb2, int* __restrict__ slots,
    float* __restrict__ out) {
  __shared__ int c[PP];
  int b = blockIdx.x;
  int t = threadIdx.x;  // 1024 threads
  c[t] = 0;
  __syncthreads();
  atomicAdd(&c[labels[b * SS + t] & (PP - 1)], 1);
  atomicAdd(&c[labels[b * SS + PP + t] & (PP - 1)], 1);
  __syncthreads();
  int cc = c[t];
  logb2[b * PP + t] = (cc > 0) ? (flog2((float)cc) - LOG2S) : NEG_INF;
  G2[b * PP + t] = 0.0f;
  if (t < 32) slots[(b << 5) + t] = 0;
  if (t == 0 && b == 0) out[0] = 0.0f;
}

__global__ __launch_bounds__(1024) void sinkhorn_persist(
    const float* __restrict__ preds, const float* __restrict__ pos,
    const float* __restrict__ logb2, float* __restrict__ F2g,
    float* __restrict__ G2g, int* __restrict__ slots,
    float* __restrict__ out) {
  // SoA LDS tiles: element-pair reads are pk-ready reg pairs (R9)
  __shared__ __align__(16) float fy0[PP], fy1[PP], fq[PP];        // 12 KB
  __shared__ __align__(16) float gx0[SS], gx1[SS], gq[SS];        // 24 KB
  __shared__ float spart;
  const int t = threadIdx.x;    // 1024 threads, 16 waves
  const int blk = blockIdx.x;   // 256 blocks = 1/CU (proven geometry)
  const int bb = blk & 7;       // XCD-LOCAL: batch = blk%8 (blk%8 = XCD)
  const int sub = blk >> 3;     // 32 blocks per batch, all on one XCD
  int* myslots = slots + (bb << 5);
  const float2* pos2 = (const float2*)pos;
  const float2* preds2 = (const float2*)preds;
  float* G2b = G2g + (bb << 10);
  float* F2b = F2g + (bb << 11);

  // ---- persistent init: x/y constants into LDS + K-scaled norms in regs
  float yr2, xr2[2];
  {
    float2 y = pos2[(bb << 10) + t];
    yr2 = y.x * y.x + y.y * y.y;
    fy0[t] = y.x;
    fy1[t] = y.y;
  }
#pragma unroll
  for (int k = 0; k < 2; ++k) {
    int e = t + (k << 10);
    float2 x = preds2[(bb << 11) + e];
    xr2[k] = x.x * x.x + x.y * x.y;
    gx0[e] = x.x;
    gx1[e] = x.y;
  }

  const int w = t >> 6, lane = t & 63;
  // f-phase: wave w owns 4 rows; lane scans 8 elem-pairs (global row index)
  const int frowb = (bb << 11) + (sub << 6) + (w << 2);
  float fk0[4], fk1[4], fc0[4];
#pragma unroll
  for (int r = 0; r < 4; ++r) {
    float2 fx = preds2[frowb + r];  // wave-uniform broadcast load
    fk0[r] = TWOK * fx.x;
    fk1[r] = TWOK * fx.y;
    fc0[r] = fmaf(K2E, fx.x * fx.x + fx.y * fx.y, -LOG2S);
  }
  // g-phase: wave w owns 2 cols; lane scans 16 elem-pairs (global col index)
  const int gcolb = (bb << 10) + (sub << 5) + (w << 1);
  float gk0[2], gk1[2], gc0[2];
#pragma unroll
  for (int c = 0; c < 2; ++c) {
    float2 gy = pos2[gcolb + c];
    gk0[c] = TWOK * gy.x;
    gk1[c] = TWOK * gy.y;
    gc0[c] = fmaf(K2E, gy.x * gy.x + gy.y * gy.y, logb2[gcolb + c]);
  }

  for (int it = 0; it < ITERS; ++it) {
    // ---- stage qy = G2 - K*y2 (4KB agent-scope reads, stride-1 LDS writes)
    fq[t] = fmaf(-K2E, yr2, coh_load(&G2b[t]));
    __syncthreads();
    // ---- f-compute: online LSE over pairs, 4 rows/lane, pk math
    {
      float m[4];
      v2f s[4];
#pragma unroll
      for (int r = 0; r < 4; ++r) { m[r] = -3.4e38f; s[r] = (v2f)(0.0f); }
#pragma unroll
      for (int ch = 0; ch < 2; ++ch) {
        v2f a0[4], a1[4], aq[4];
#pragma unroll
        for (int i = 0; i < 4; ++i) {
          int pi = (ch << 8) + (i << 6) + lane;  // pair index, consecutive
          a0[i] = *(const v2f*)&fy0[pi << 1];
          a1[i] = *(const v2f*)&fy1[pi << 1];
          aq[i] = *(const v2f*)&fq[pi << 1];
        }
#pragma unroll
        for (int r = 0; r < 4; ++r) {
          v2f K0 = (v2f)(fk0[r]), K1 = (v2f)(fk1[r]);
          v2f u0 = vfma(K0, a0[0], vfma(K1, a1[0], aq[0]));
          v2f u1 = vfma(K0, a0[1], vfma(K1, a1[1], aq[1]));
          v2f u2 = vfma(K0, a0[2], vfma(K1, a1[2], aq[2]));
          v2f u3 = vfma(K0, a0[3], vfma(K1, a1[3], aq[3]));
          v2f cm2 = vmax(vmax(u0, u1), vmax(u2, u3));
          float mn = fmaxf(m[r], fmaxf(cm2.x, cm2.y));
          float sc = fexp2(m[r] - mn);
          v2f mn2 = (v2f)(mn);
          v2f d0 = u0 - mn2, d1 = u1 - mn2, d2 = u2 - mn2, d3 = u3 - mn2;
          v2f e0 = {fexp2(d0.x), fexp2(d0.y)};
          v2f e1 = {fexp2(d1.x), fexp2(d1.y)};
          v2f e2 = {fexp2(d2.x), fexp2(d2.y)};
          v2f e3 = {fexp2(d3.x), fexp2(d3.y)};
          s[r] = vfma(s[r], (v2f)(sc), (e0 + e1) + (e2 + e3));
          m[r] = mn;
        }
      }
      // lane merge; lane r keeps value r; lanes 0..3 store coalesced
      float fout = 0.0f;
#pragma unroll
      for (int r = 0; r < 4; ++r) {
        float M = m[r];
#pragma unroll
        for (int off = 1; off <= 32; off <<= 1)
          M = fmaxf(M, __shfl_xor(M, off, 64));
        float sr = (s[r].x + s[r].y) * fexp2(m[r] - M);
#pragma unroll
        for (int off = 1; off <= 32; off <<= 1) sr += __shfl_xor(sr, off, 64);
        float v = fc0[r] - M - flog2(sr);
        if (lane == r) fout = v;
      }
      if (lane < 4) coh_store(&F2g[frowb + lane], fout);
    }
    batch_barrier(myslots, sub, 2 * it + 1, w, lane);

    // ---- stage qx = F2 - K*x2 (8KB agent-scope reads)
#pragma unroll
    for (int k = 0; k < 2; ++k) {
      int e = t + (k << 10);
      gq[e] = fmaf(-K2E, xr2[k], coh_load(&F2b[e]));
    }
    __syncthreads();
    // ---- g-compute: online LSE over pairs, 2 cols/lane, pk math
    {
      float m[2];
      v2f s[2];
#pragma unroll
      for (int c = 0; c < 2; ++c) { m[c] = -3.4e38f; s[c] = (v2f)(0.0f); }
#pragma unroll
      for (int ch = 0; ch < 4; ++ch) {
        v2f a0[4], a1[4], aq[4];
#pragma unroll
        for (int i = 0; i < 4; ++i) {
          int pi = (ch << 8) + (i << 6) + lane;
          a0[i] = *(const v2f*)&gx0[pi << 1];
          a1[i] = *(const v2f*)&gx1[pi << 1];
          aq[i] = *(const v2f*)&gq[pi << 1];
        }
#pragma unroll
        for (int c = 0; c < 2; ++c) {
          v2f K0 = (v2f)(gk0[c]), K1 = (v2f)(gk1[c]);
          v2f u0 = vfma(K0, a0[0], vfma(K1, a1[0], aq[0]));
          v2f u1 = vfma(K0, a0[1], vfma(K1, a1[1], aq[1]));
          v2f u2 = vfma(K0, a0[2], vfma(K1, a1[2], aq[2]));
          v2f u3 = vfma(K0, a0[3], vfma(K1, a1[3], aq[3]));
          v2f cm2 = vmax(vmax(u0, u1), vmax(u2, u3));
          float mn = fmaxf(m[c], fmaxf(cm2.x, cm2.y));
          float sc = fexp2(m[c] - mn);
          v2f mn2 = (v2f)(mn);
          v2f d0 = u0 - mn2, d1 = u1 - mn2, d2 = u2 - mn2, d3 = u3 - mn2;
          v2f e0 = {fexp2(d0.x), fexp2(d0.y)};
          v2f e1 = {fexp2(d1.x), fexp2(d1.y)};
          v2f e2 = {fexp2(d2.x), fexp2(d2.y)};
          v2f e3 = {fexp2(d3.x), fexp2(d3.y)};
          s[c] = vfma(s[c], (v2f)(sc), (e0 + e1) + (e2 + e3));
          m[c] = mn;
        }
      }
      float gout = 0.0f;
#pragma unroll
      for (int c = 0; c < 2; ++c) {
        float M = m[c];
#pragma unroll
        for (int off = 1; off <= 32; off <<= 1)
          M = fmaxf(M, __shfl_xor(M, off, 64));
        float sr = (s[c].x + s[c].y) * fexp2(m[c] - M);
#pragma unroll
        for (int off = 1; off <= 32; off <<= 1) sr += __shfl_xor(sr, off, 64);
        float v = gc0[c] - M - flog2(sr);
        if (lane == c) gout = v;
      }
      if (lane < 2) coh_store(&G2g[gcolb + lane], gout);
    }
    batch_barrier(myslots, sub, 2 * it + 2, w, lane);
  }

  // ---- fused final: restage qy with final G2, rowsum over own 64 rows
  if (t == 0) spart = 0.0f;
  fq[t] = fmaf(-K2E, yr2, coh_load(&G2b[t]));
  __syncthreads();
  float acc = 0.0f;
#pragma unroll
  for (int rr = 0; rr < 4; ++rr) {
    int row = frowb + rr;
    float2 x = preds2[row];
    float x2 = x.x * x.x + x.y * x.y;
    float qx = fmaf(-K2E, x2, coh_load(&F2g[row]));
#pragma unroll
    for (int i = 0; i < 16; ++i) {
      int p = (i << 6) + lane;
      float ay0 = fy0[p], ay1 = fy1[p], aqz = fq[p];
      float y2 = fmaf(ay0, ay0, ay1 * ay1);
      float tt = fmaf(x.y, ay1, x.x * ay0);
      float c = fmaxf(x2 + y2 - 2.0f * tt, 0.0f);  // clamped cost
      float v2 = fmaf(TWOK, tt, aqz + qx);         // -K*C' + F2 + G2 (base-2)
      acc = fmaf(fexp2(v2), c, acc);               // c==0 kills C'<0 case
    }
  }
#pragma unroll
  for (int off = 32; off; off >>= 1) acc += __shfl_xor(acc, off, 64);
  if (lane == 0) atomicAdd(&spart, acc);
  __syncthreads();
  if (t == 0) atomicAdd(out, spart * (1.0f / (float)BB));
}

extern "C" void kernel_launch(void* const* d_in, const int* in_sizes, int n_in,
                              void* d_out, int out_size, void* d_ws,
                              size_t ws_size, hipStream_t stream) {
  const float* preds = (const float*)d_in[0];  // [B,S,2]
  const int* labels = (const int*)d_in[1];     // [B,S]
  const float* pos = (const float*)d_in[2];    // [B,P,2]
  float* out = (float*)d_out;
  char* ws = (char*)d_ws;
  float* G2 = (float*)(ws);
  float* F2 = (float*)(ws + 32768);
  float* logb2 = (float*)(ws + 98304);
  int* slots = (int*)(ws + 131072);

  hipLaunchKernelGGL(setup_kernel, dim3(BB), dim3(1024), 0, stream, labels, G2,
                     logb2, slots, out);
  hipLaunchKernelGGL(sinkhorn_persist, dim3(NBLK), dim3(NTHR), 0, stream,
                     preds, pos, logb2, F2, G2, slots, out);
}